// Round 4
// baseline (6527.934 us; speedup 1.0000x reference)
//
#include <hip/hip_runtime.h>
#include <hip/hip_bf16.h>
#include <math.h>

// Problem dims (fixed by reference)
#define NTOK 98304      // 32768 * 3
#define DIN  256
#define DE   512
#define DH   512
#define DC   64
#define NCODE 1024
#define CHUNK 16384     // tokens per pipeline chunk (6 chunks)

typedef _Float16 half8 __attribute__((ext_vector_type(8)));
typedef float f32x4 __attribute__((ext_vector_type(4)));

__device__ __forceinline__ float gelu_f(float x) {
    const float k0 = 0.7978845608028654f;  // sqrt(2/pi)
    const float k1 = 0.044715f;
    float x3 = x * x * x;
    return 0.5f * x * (1.0f + tanhf(k0 * (x + k1 * x3)));
}

// split fp32 -> (hi fp16, lo fp16) packed in uint32 (lo in high 16 bits)
__device__ __forceinline__ unsigned int split_pack(float x) {
    _Float16 hi = (_Float16)x;
    float hif = (float)hi;
    _Float16 lo = (_Float16)(x - hif);
    unsigned short uh = __builtin_bit_cast(unsigned short, hi);
    unsigned short ul = __builtin_bit_cast(unsigned short, lo);
    return (unsigned int)uh | ((unsigned int)ul << 16);
}

// W[K][N] fp32 -> Wt[N][K] packed half2(hi,lo)
__global__ __launch_bounds__(256)
void transpose_split(const float* __restrict__ W, unsigned int* __restrict__ Wt,
                     int K, int N)
{
    int e = blockIdx.x * 256 + threadIdx.x;
    if (e >= K * N) return;
    int k = e / N, n = e % N;
    Wt[(size_t)n * K + k] = split_pack(W[e]);
}

// ======================= MLP GEMM (fp16x3 MFMA) =======================
template<int BN, bool A_F32, bool EMIT_F32>
__global__ __launch_bounds__(256, 2)
void gemm_f16x3(const void* __restrict__ Aptr, const unsigned int* __restrict__ Wt,
                const float* __restrict__ bias, void* __restrict__ Cptr,
                int M, int N, int K)
{
    constexpr int BM = 128, BK = 32;
    constexpr int WGM = (BN == 128) ? 2 : 4;
    constexpr int WAVE_M = BM / WGM;
    constexpr int MT = WAVE_M / 16;
    constexpr int NT = 4;

    __shared__ _Float16 Ah[BM][40], Al[BM][40];
    __shared__ _Float16 Bh[BN][40], Bl[BN][40];

    const int tid  = threadIdx.x;
    const int lane = tid & 63, wid = tid >> 6;
    const int lm   = lane & 15, quad = lane >> 4;
    const int wave_m = (BN == 128) ? (wid & 1) * 64 : wid * 32;
    const int wave_n = (BN == 128) ? (wid >> 1) * 64 : 0;
    const int m0 = blockIdx.y * BM, n0 = blockIdx.x * BN;

    f32x4 acc[MT][NT];
#pragma unroll
    for (int mi = 0; mi < MT; ++mi)
#pragma unroll
        for (int ni = 0; ni < NT; ++ni) acc[mi][ni] = (f32x4)(0.f);

    for (int k0 = 0; k0 < K; k0 += BK) {
#pragma unroll
        for (int i = 0; i < (BM * (BK / 4)) / 256; ++i) {
            int s = tid + i * 256;
            int row = s >> 3, kc = (s & 7) * 4;
            unsigned short h[4], l[4];
            if (A_F32) {
                const float* A = (const float*)Aptr;
                float4 v = *(const float4*)(A + (size_t)(m0 + row) * K + k0 + kc);
                float vv[4] = {v.x, v.y, v.z, v.w};
#pragma unroll
                for (int j = 0; j < 4; ++j) {
                    unsigned int p = split_pack(vv[j]);
                    h[j] = p & 0xffff; l[j] = p >> 16;
                }
            } else {
                const unsigned int* A = (const unsigned int*)Aptr;
                uint4 v = *(const uint4*)(A + (size_t)(m0 + row) * K + k0 + kc);
                unsigned int vv[4] = {v.x, v.y, v.z, v.w};
#pragma unroll
                for (int j = 0; j < 4; ++j) { h[j] = vv[j] & 0xffff; l[j] = vv[j] >> 16; }
            }
            uint2 ph, pl;
            ph.x = (unsigned int)h[0] | ((unsigned int)h[1] << 16);
            ph.y = (unsigned int)h[2] | ((unsigned int)h[3] << 16);
            pl.x = (unsigned int)l[0] | ((unsigned int)l[1] << 16);
            pl.y = (unsigned int)l[2] | ((unsigned int)l[3] << 16);
            *(uint2*)&Ah[row][kc] = ph;
            *(uint2*)&Al[row][kc] = pl;
        }
#pragma unroll
        for (int i = 0; i < (BN * (BK / 4)) / 256; ++i) {
            int s = tid + i * 256;
            int row = s >> 3, kc = (s & 7) * 4;
            uint4 v = *(const uint4*)(Wt + (size_t)(n0 + row) * K + k0 + kc);
            unsigned int vv[4] = {v.x, v.y, v.z, v.w};
            unsigned short h[4], l[4];
#pragma unroll
            for (int j = 0; j < 4; ++j) { h[j] = vv[j] & 0xffff; l[j] = vv[j] >> 16; }
            uint2 ph, pl;
            ph.x = (unsigned int)h[0] | ((unsigned int)h[1] << 16);
            ph.y = (unsigned int)h[2] | ((unsigned int)h[3] << 16);
            pl.x = (unsigned int)l[0] | ((unsigned int)l[1] << 16);
            pl.y = (unsigned int)l[2] | ((unsigned int)l[3] << 16);
            *(uint2*)&Bh[row][kc] = ph;
            *(uint2*)&Bl[row][kc] = pl;
        }
        __syncthreads();

        half8 ahf[MT], alf[MT], bhf[NT], blf[NT];
#pragma unroll
        for (int mi = 0; mi < MT; ++mi) {
            int r = wave_m + mi * 16 + lm;
            ahf[mi] = *(const half8*)&Ah[r][quad * 8];
            alf[mi] = *(const half8*)&Al[r][quad * 8];
        }
#pragma unroll
        for (int ni = 0; ni < NT; ++ni) {
            int r = wave_n + ni * 16 + lm;
            bhf[ni] = *(const half8*)&Bh[r][quad * 8];
            blf[ni] = *(const half8*)&Bl[r][quad * 8];
        }
#pragma unroll
        for (int mi = 0; mi < MT; ++mi)
#pragma unroll
            for (int ni = 0; ni < NT; ++ni) {
                acc[mi][ni] = __builtin_amdgcn_mfma_f32_16x16x32_f16(ahf[mi], bhf[ni], acc[mi][ni], 0, 0, 0);
                acc[mi][ni] = __builtin_amdgcn_mfma_f32_16x16x32_f16(ahf[mi], blf[ni], acc[mi][ni], 0, 0, 0);
                acc[mi][ni] = __builtin_amdgcn_mfma_f32_16x16x32_f16(alf[mi], bhf[ni], acc[mi][ni], 0, 0, 0);
            }
        __syncthreads();
    }

#pragma unroll
    for (int ni = 0; ni < NT; ++ni) {
        int col = n0 + wave_n + ni * 16 + lm;
        float bv = bias[col];
#pragma unroll
        for (int mi = 0; mi < MT; ++mi) {
            int rowbase = m0 + wave_m + mi * 16 + quad * 4;
#pragma unroll
            for (int r = 0; r < 4; ++r) {
                float g = gelu_f(acc[mi][ni][r] + bv);
                if (EMIT_F32) {
                    ((float*)Cptr)[(size_t)(rowbase + r) * N + col] = g;
                } else {
                    ((unsigned int*)Cptr)[(size_t)(rowbase + r) * N + col] = split_pack(g);
                }
            }
        }
    }
}

// ======================= VQ prep =======================
// emb [64][1024] fp32 -> embT hi/lo planes [1024][64] f16
__global__ __launch_bounds__(256)
void prep_emb(const float* __restrict__ emb, _Float16* __restrict__ ebh,
              _Float16* __restrict__ ebl)
{
    int e = blockIdx.x * 256 + threadIdx.x;   // 65536
    int c = e >> 10, n = e & 1023;
    float v = emb[e];
    _Float16 h = (_Float16)v;
    _Float16 l = (_Float16)(v - (float)h);
    ebh[(size_t)n * DC + c] = h;
    ebl[(size_t)n * DC + c] = l;
}

__global__ __launch_bounds__(256)
void e2_kernel(const float* __restrict__ emb, float* __restrict__ e2)
{
    int n = blockIdx.x * 256 + threadIdx.x;   // 1024
    float s = 0.f;
#pragma unroll
    for (int c = 0; c < DC; ++c) { float e = emb[(size_t)c * NCODE + n]; s = fmaf(e, e, s); }
    e2[n] = s;
}

// ======================= VQ main (MFMA fp16x4 distances) =======================
// 64 tokens/block. d = |e|^2 - 2 x.e ; x.e via 4-term split MFMA (~fp32 quality).
__global__ __launch_bounds__(256, 2)
void vq_mfma_kernel(const float* __restrict__ lat, const float* __restrict__ emb,
                    const _Float16* __restrict__ ebh, const _Float16* __restrict__ ebl,
                    const float* __restrict__ e2,
                    float* __restrict__ quant_out, float* __restrict__ encidx_out,
                    int* __restrict__ codes_out, unsigned int* __restrict__ counts,
                    float* __restrict__ sum_sq)
{
    __shared__ _Float16 Ah[64][72], Al[64][72];   // pad 72: lane stride 36 dw -> 2-way banks (free)
    __shared__ float e2s[NCODE];
    __shared__ float red_d[64][17];
    __shared__ int   red_i[64][17];
    __shared__ int   sidx[64];
    __shared__ float wred[4];

    const int tid = threadIdx.x, lane = tid & 63, wave = tid >> 6;
    const int lm = lane & 15, quad = lane >> 4;
    const int tok0 = blockIdx.x * 64;

#pragma unroll
    for (int i = 0; i < 4; ++i) { int k = tid + i * 256; e2s[k] = e2[k]; }
#pragma unroll
    for (int i = 0; i < 4; ++i) {
        int idx = tid + i * 256;          // float4 slot 0..1023
        int row = idx >> 4, c4 = (idx & 15) * 4;
        float4 v = *(const float4*)(lat + (size_t)(tok0 + row) * DC + c4);
        float vv[4] = {v.x, v.y, v.z, v.w};
        unsigned short h[4], l[4];
#pragma unroll
        for (int j = 0; j < 4; ++j) {
            _Float16 hh = (_Float16)vv[j];
            _Float16 ll = (_Float16)(vv[j] - (float)hh);
            h[j] = __builtin_bit_cast(unsigned short, hh);
            l[j] = __builtin_bit_cast(unsigned short, ll);
        }
        uint2 ph, pl;
        ph.x = (unsigned int)h[0] | ((unsigned int)h[1] << 16);
        ph.y = (unsigned int)h[2] | ((unsigned int)h[3] << 16);
        pl.x = (unsigned int)l[0] | ((unsigned int)l[1] << 16);
        pl.y = (unsigned int)l[2] | ((unsigned int)l[3] << 16);
        *(uint2*)&Ah[row][c4] = ph;
        *(uint2*)&Al[row][c4] = pl;
    }
    __syncthreads();

    float bd[4]; int bi[4];
#pragma unroll
    for (int r = 0; r < 4; ++r) { bd[r] = INFINITY; bi[r] = 0; }

    for (int k0 = 0; k0 < NCODE; k0 += 64) {
        f32x4 acc[4];
#pragma unroll
        for (int ni = 0; ni < 4; ++ni) acc[ni] = (f32x4)(0.f);
#pragma unroll
        for (int ks = 0; ks < 2; ++ks) {
            half8 ah = *(const half8*)&Ah[wave * 16 + lm][ks * 32 + quad * 8];
            half8 al = *(const half8*)&Al[wave * 16 + lm][ks * 32 + quad * 8];
#pragma unroll
            for (int ni = 0; ni < 4; ++ni) {
                int code = k0 + ni * 16 + lm;
                half8 bh = *(const half8*)(ebh + (size_t)code * DC + ks * 32 + quad * 8);
                half8 bl = *(const half8*)(ebl + (size_t)code * DC + ks * 32 + quad * 8);
                acc[ni] = __builtin_amdgcn_mfma_f32_16x16x32_f16(ah, bh, acc[ni], 0, 0, 0);
                acc[ni] = __builtin_amdgcn_mfma_f32_16x16x32_f16(ah, bl, acc[ni], 0, 0, 0);
                acc[ni] = __builtin_amdgcn_mfma_f32_16x16x32_f16(al, bh, acc[ni], 0, 0, 0);
                acc[ni] = __builtin_amdgcn_mfma_f32_16x16x32_f16(al, bl, acc[ni], 0, 0, 0);
            }
        }
#pragma unroll
        for (int ni = 0; ni < 4; ++ni) {
            int code = k0 + ni * 16 + lm;
            float ee = e2s[code];
#pragma unroll
            for (int r = 0; r < 4; ++r) {
                float d = ee - 2.f * acc[ni][r];
                if (d < bd[r]) { bd[r] = d; bi[r] = code; }   // ascending code order => first-min
            }
        }
    }

    // lane's 4 tokens: wave*16 + quad*4 + r ; cross-lane (16 cols) reduce via LDS
#pragma unroll
    for (int r = 0; r < 4; ++r) {
        int t = wave * 16 + quad * 4 + r;
        red_d[t][lm] = bd[r];
        red_i[t][lm] = bi[r];
    }
    __syncthreads();
    if (tid < 64) {
        float d0 = red_d[tid][0]; int i0 = red_i[tid][0];
        for (int x = 1; x < 16; ++x) {
            float d = red_d[tid][x]; int i = red_i[tid][x];
            if (d < d0 || (d == d0 && i < i0)) { d0 = d; i0 = i; }
        }
        sidx[tid] = i0;
        encidx_out[tok0 + tid] = (float)i0;
        codes_out[tok0 + tid] = i0;
        atomicAdd(&counts[i0], 1u);
    }
    __syncthreads();

    // phase 2: quantized gather (exact fp32 emb), loss partial
    const int t2 = tid >> 2;
    const int g  = tid & 3;
    const int code = sidx[t2];
    float lsum = 0.f;
#pragma unroll
    for (int q = 0; q < 4; ++q) {
        int c0 = g * 16 + q * 4;
        float4 xv = *(const float4*)(lat + (size_t)(tok0 + t2) * DC + c0);
        float xx[4] = {xv.x, xv.y, xv.z, xv.w};
        float qv[4];
#pragma unroll
        for (int j = 0; j < 4; ++j) {
            qv[j] = emb[(size_t)(c0 + j) * NCODE + code];
            float df = qv[j] - xx[j];
            lsum = fmaf(df, df, lsum);
        }
        float4 v; v.x = qv[0]; v.y = qv[1]; v.z = qv[2]; v.w = qv[3];
        *(float4*)(quant_out + (size_t)(tok0 + t2) * DC + c0) = v;
    }
#pragma unroll
    for (int o = 32; o > 0; o >>= 1) lsum += __shfl_down(lsum, o);
    if ((tid & 63) == 0) wred[tid >> 6] = lsum;
    __syncthreads();
    if (tid == 0) atomicAdd(sum_sq, wred[0] + wred[1] + wred[2] + wred[3]);
}

// ======================= dw via bucketing (no fp atomics) =======================
__global__ __launch_bounds__(1024)
void scan_kernel(const unsigned int* __restrict__ counts, int* __restrict__ offs)
{
    __shared__ int s[1024];
    int t = threadIdx.x;
    int v = (int)counts[t];
    s[t] = v; __syncthreads();
    for (int d = 1; d < 1024; d <<= 1) {
        int x = (t >= d) ? s[t - d] : 0;
        __syncthreads();
        s[t] += x;
        __syncthreads();
    }
    offs[t] = s[t] - v;   // exclusive
}

__global__ __launch_bounds__(256)
void scatter_kernel(const int* __restrict__ codes, const int* __restrict__ offs,
                    unsigned int* __restrict__ cursors, int* __restrict__ bucket)
{
    int t = blockIdx.x * 256 + threadIdx.x;
    int c = codes[t];
    int p = (int)atomicAdd(&cursors[c], 1u);
    bucket[offs[c] + p] = t;
}

__global__ __launch_bounds__(64)
void dw_kernel(const float* __restrict__ lat, const int* __restrict__ bucket,
               const int* __restrict__ offs, const unsigned int* __restrict__ counts,
               float* __restrict__ dw)
{
    int code = blockIdx.x;
    int c = threadIdx.x;
    int base = offs[code];
    int n = (int)counts[code];
    float s = 0.f;
    for (int i = 0; i < n; ++i)
        s += lat[(size_t)bucket[base + i] * DC + c];
    dw[(size_t)c * NCODE + code] = s;
}

// ======================= finalize =======================
__global__ __launch_bounds__(1024)
void finalize_kernel(const unsigned int* __restrict__ counts,
                     const float* __restrict__ dw,
                     const float* __restrict__ ema_ch,
                     const float* __restrict__ ema_dw,
                     const float* __restrict__ sum_sq,
                     float* __restrict__ out_loss, float* __restrict__ out_perp,
                     float* __restrict__ out_newemb)
{
    __shared__ float sred[1024];
    const int k = threadIdx.x;
    const float debias = (float)(1.0 - pow(0.99, 1001.0));
    float cnt = (float)counts[k];
    float cs  = (ema_ch[k] * 0.99f + cnt * 0.01f) / debias;

    sred[k] = cs; __syncthreads();
    for (int s = 512; s > 0; s >>= 1) { if (k < s) sred[k] += sred[k + s]; __syncthreads(); }
    float n = sred[0];
    __syncthreads();

    float p = cnt / 98304.0f;
    sred[k] = p * logf(p + 1e-10f);
    __syncthreads();
    for (int s = 512; s > 0; s >>= 1) { if (k < s) sred[k] += sred[k + s]; __syncthreads(); }
    if (k == 0) {
        out_perp[0] = expf(-sred[0]);
        out_loss[0] = 0.25f * sum_sq[0] / 6291456.0f;
    }

    float stable = (cs + 1e-5f) / (n + 1024.0f * 1e-5f) * n;
#pragma unroll
    for (int c = 0; c < 64; ++c) {
        size_t o = (size_t)c * 1024 + k;
        out_newemb[o] = ((ema_dw[o] * 0.99f + dw[o] * 0.01f) / debias) / stable;
    }
}

extern "C" void kernel_launch(void* const* d_in, const int* in_sizes, int n_in,
                              void* d_out, int out_size, void* d_ws, size_t ws_size,
                              hipStream_t stream)
{
    (void)in_sizes; (void)n_in; (void)out_size; (void)ws_size;
    const float* states = (const float*)d_in[0];
    const float* w_se   = (const float*)d_in[1];
    const float* b_se   = (const float*)d_in[2];
    const float* w0     = (const float*)d_in[3];
    const float* b0     = (const float*)d_in[4];
    const float* w1     = (const float*)d_in[5];
    const float* b1     = (const float*)d_in[6];
    const float* w2     = (const float*)d_in[7];
    const float* b2     = (const float*)d_in[8];
    const float* emb    = (const float*)d_in[9];
    const float* ema_ch = (const float*)d_in[10];
    const float* ema_dw = (const float*)d_in[11];

    float* out        = (float*)d_out;
    float* q_out      = out;                    // 6291456
    float* loss_out   = out + 6291456;          // 1
    float* perp_out   = out + 6291457;          // 1
    float* idx_out    = out + 6291458;          // 98304
    float* newemb_out = out + 6389762;          // 65536

    // ---- workspace layout ----
    char* ws = (char*)d_ws;
    size_t o = 0;
    unsigned int* counts  = (unsigned int*)(ws + o); o += 4096;
    unsigned int* cursors = (unsigned int*)(ws + o); o += 4096;
    float*        sumsq   = (float*)(ws + o);        o += 256;      // zeroed region ends 8448
    int*          offs    = (int*)(ws + o);          o += 4096;
    int*          codes   = (int*)(ws + o);          o += (size_t)NTOK * 4;
    int*          bucket  = (int*)(ws + o);          o += (size_t)NTOK * 4;
    float*        e2b     = (float*)(ws + o);        o += 4096;
    _Float16*     ebh     = (_Float16*)(ws + o);     o += (size_t)NCODE * DC * 2;
    _Float16*     ebl     = (_Float16*)(ws + o);     o += (size_t)NCODE * DC * 2;
    float*        dwb     = (float*)(ws + o);        o += (size_t)DC * NCODE * 4;
    unsigned int* wse_t   = (unsigned int*)(ws + o); o += (size_t)DIN * DE * 4;
    unsigned int* w0t     = (unsigned int*)(ws + o); o += (size_t)DE * DH * 4;
    unsigned int* w1t     = (unsigned int*)(ws + o); o += (size_t)DH * DH * 4;
    unsigned int* w2t     = (unsigned int*)(ws + o); o += (size_t)DH * DC * 4;
    unsigned int* bufA    = (unsigned int*)(ws + o); o += (size_t)CHUNK * DE * 4;
    unsigned int* bufB    = (unsigned int*)(ws + o); o += (size_t)CHUNK * DH * 4;
    float*        lat     = (float*)(ws + o);        o += (size_t)NTOK * DC * 4;

    hipMemsetAsync(d_ws, 0, 8448, stream);   // counts + cursors + sumsq

    // weight/codebook prep (tiny)
    transpose_split<<<dim3((DIN * DE + 255) / 256), dim3(256), 0, stream>>>(w_se, wse_t, DIN, DE);
    transpose_split<<<dim3((DE * DH + 255) / 256), dim3(256), 0, stream>>>(w0, w0t, DE, DH);
    transpose_split<<<dim3((DH * DH + 255) / 256), dim3(256), 0, stream>>>(w1, w1t, DH, DH);
    transpose_split<<<dim3((DH * DC + 255) / 256), dim3(256), 0, stream>>>(w2, w2t, DH, DC);
    prep_emb<<<dim3(256), dim3(256), 0, stream>>>(emb, ebh, ebl);
    e2_kernel<<<dim3(4), dim3(256), 0, stream>>>(emb, e2b);

    dim3 blk(256);
    const int MBLK = CHUNK / 128;
    for (int c = 0; c < NTOK / CHUNK; ++c) {
        size_t off = (size_t)c * CHUNK;
        gemm_f16x3<128, true,  false><<<dim3(DE / 128, MBLK), blk, 0, stream>>>(
            states + off * DIN, wse_t, b_se, bufA, CHUNK, DE, DIN);
        gemm_f16x3<128, false, false><<<dim3(DH / 128, MBLK), blk, 0, stream>>>(
            bufA, w0t, b0, bufB, CHUNK, DH, DE);
        gemm_f16x3<128, false, false><<<dim3(DH / 128, MBLK), blk, 0, stream>>>(
            bufB, w1t, b1, bufA, CHUNK, DH, DH);
        gemm_f16x3<64,  false, true ><<<dim3(1, MBLK), blk, 0, stream>>>(
            bufA, w2t, b2, lat + off * DC, CHUNK, DC, DH);
    }

    vq_mfma_kernel<<<dim3(NTOK / 64), blk, 0, stream>>>(
        lat, emb, ebh, ebl, e2b, q_out, idx_out, codes, counts, sumsq);

    scan_kernel<<<dim3(1), dim3(1024), 0, stream>>>(counts, offs);
    scatter_kernel<<<dim3(NTOK / 256), blk, 0, stream>>>(codes, offs, cursors, bucket);
    dw_kernel<<<dim3(NCODE), dim3(64), 0, stream>>>(lat, bucket, offs, counts, dwb);

    finalize_kernel<<<dim3(1), dim3(1024), 0, stream>>>(counts, dwb, ema_ch, ema_dw, sumsq,
                                                        loss_out, perp_out, newemb_out);
}

// Round 5
// 1376.802 us; speedup vs baseline: 4.7414x; 4.7414x over previous
//
#include <hip/hip_runtime.h>
#include <hip/hip_bf16.h>
#include <math.h>

// Problem dims (fixed by reference)
#define NTOK 98304      // 32768 * 3
#define DIN  256
#define DE   512
#define DH   512
#define DC   64
#define NCODE 1024
#define CHUNK 16384     // tokens per pipeline chunk (6 chunks)
#define DWCHUNK 1024    // tokens per dw block (skew-proof parallelism)

typedef _Float16 half8 __attribute__((ext_vector_type(8)));
typedef float f32x4 __attribute__((ext_vector_type(4)));

__device__ __forceinline__ float gelu_f(float x) {
    const float k0 = 0.7978845608028654f;  // sqrt(2/pi)
    const float k1 = 0.044715f;
    float x3 = x * x * x;
    return 0.5f * x * (1.0f + tanhf(k0 * (x + k1 * x3)));
}

// split fp32 -> (hi fp16, lo fp16) packed in uint32 (lo in high 16 bits)
__device__ __forceinline__ unsigned int split_pack(float x) {
    _Float16 hi = (_Float16)x;
    float hif = (float)hi;
    _Float16 lo = (_Float16)(x - hif);
    unsigned short uh = __builtin_bit_cast(unsigned short, hi);
    unsigned short ul = __builtin_bit_cast(unsigned short, lo);
    return (unsigned int)uh | ((unsigned int)ul << 16);
}

// W[K][N] fp32 -> Wt[N][K] packed half2(hi,lo)
__global__ __launch_bounds__(256)
void transpose_split(const float* __restrict__ W, unsigned int* __restrict__ Wt,
                     int K, int N)
{
    int e = blockIdx.x * 256 + threadIdx.x;
    if (e >= K * N) return;
    int k = e / N, n = e % N;
    Wt[(size_t)n * K + k] = split_pack(W[e]);
}

// ======================= MLP GEMM (fp16x3 MFMA) =======================
template<int BN, bool A_F32, bool EMIT_F32>
__global__ __launch_bounds__(256, 2)
void gemm_f16x3(const void* __restrict__ Aptr, const unsigned int* __restrict__ Wt,
                const float* __restrict__ bias, void* __restrict__ Cptr,
                int M, int N, int K)
{
    constexpr int BM = 128, BK = 32;
    constexpr int WGM = (BN == 128) ? 2 : 4;
    constexpr int WAVE_M = BM / WGM;
    constexpr int MT = WAVE_M / 16;
    constexpr int NT = 4;

    __shared__ _Float16 Ah[BM][40], Al[BM][40];
    __shared__ _Float16 Bh[BN][40], Bl[BN][40];

    const int tid  = threadIdx.x;
    const int lane = tid & 63, wid = tid >> 6;
    const int lm   = lane & 15, quad = lane >> 4;
    const int wave_m = (BN == 128) ? (wid & 1) * 64 : wid * 32;
    const int wave_n = (BN == 128) ? (wid >> 1) * 64 : 0;
    const int m0 = blockIdx.y * BM, n0 = blockIdx.x * BN;

    f32x4 acc[MT][NT];
#pragma unroll
    for (int mi = 0; mi < MT; ++mi)
#pragma unroll
        for (int ni = 0; ni < NT; ++ni) acc[mi][ni] = (f32x4)(0.f);

    for (int k0 = 0; k0 < K; k0 += BK) {
#pragma unroll
        for (int i = 0; i < (BM * (BK / 4)) / 256; ++i) {
            int s = tid + i * 256;
            int row = s >> 3, kc = (s & 7) * 4;
            unsigned short h[4], l[4];
            if (A_F32) {
                const float* A = (const float*)Aptr;
                float4 v = *(const float4*)(A + (size_t)(m0 + row) * K + k0 + kc);
                float vv[4] = {v.x, v.y, v.z, v.w};
#pragma unroll
                for (int j = 0; j < 4; ++j) {
                    unsigned int p = split_pack(vv[j]);
                    h[j] = p & 0xffff; l[j] = p >> 16;
                }
            } else {
                const unsigned int* A = (const unsigned int*)Aptr;
                uint4 v = *(const uint4*)(A + (size_t)(m0 + row) * K + k0 + kc);
                unsigned int vv[4] = {v.x, v.y, v.z, v.w};
#pragma unroll
                for (int j = 0; j < 4; ++j) { h[j] = vv[j] & 0xffff; l[j] = vv[j] >> 16; }
            }
            uint2 ph, pl;
            ph.x = (unsigned int)h[0] | ((unsigned int)h[1] << 16);
            ph.y = (unsigned int)h[2] | ((unsigned int)h[3] << 16);
            pl.x = (unsigned int)l[0] | ((unsigned int)l[1] << 16);
            pl.y = (unsigned int)l[2] | ((unsigned int)l[3] << 16);
            *(uint2*)&Ah[row][kc] = ph;
            *(uint2*)&Al[row][kc] = pl;
        }
#pragma unroll
        for (int i = 0; i < (BN * (BK / 4)) / 256; ++i) {
            int s = tid + i * 256;
            int row = s >> 3, kc = (s & 7) * 4;
            uint4 v = *(const uint4*)(Wt + (size_t)(n0 + row) * K + k0 + kc);
            unsigned int vv[4] = {v.x, v.y, v.z, v.w};
            unsigned short h[4], l[4];
#pragma unroll
            for (int j = 0; j < 4; ++j) { h[j] = vv[j] & 0xffff; l[j] = vv[j] >> 16; }
            uint2 ph, pl;
            ph.x = (unsigned int)h[0] | ((unsigned int)h[1] << 16);
            ph.y = (unsigned int)h[2] | ((unsigned int)h[3] << 16);
            pl.x = (unsigned int)l[0] | ((unsigned int)l[1] << 16);
            pl.y = (unsigned int)l[2] | ((unsigned int)l[3] << 16);
            *(uint2*)&Bh[row][kc] = ph;
            *(uint2*)&Bl[row][kc] = pl;
        }
        __syncthreads();

        half8 ahf[MT], alf[MT], bhf[NT], blf[NT];
#pragma unroll
        for (int mi = 0; mi < MT; ++mi) {
            int r = wave_m + mi * 16 + lm;
            ahf[mi] = *(const half8*)&Ah[r][quad * 8];
            alf[mi] = *(const half8*)&Al[r][quad * 8];
        }
#pragma unroll
        for (int ni = 0; ni < NT; ++ni) {
            int r = wave_n + ni * 16 + lm;
            bhf[ni] = *(const half8*)&Bh[r][quad * 8];
            blf[ni] = *(const half8*)&Bl[r][quad * 8];
        }
#pragma unroll
        for (int mi = 0; mi < MT; ++mi)
#pragma unroll
            for (int ni = 0; ni < NT; ++ni) {
                acc[mi][ni] = __builtin_amdgcn_mfma_f32_16x16x32_f16(ahf[mi], bhf[ni], acc[mi][ni], 0, 0, 0);
                acc[mi][ni] = __builtin_amdgcn_mfma_f32_16x16x32_f16(ahf[mi], blf[ni], acc[mi][ni], 0, 0, 0);
                acc[mi][ni] = __builtin_amdgcn_mfma_f32_16x16x32_f16(alf[mi], bhf[ni], acc[mi][ni], 0, 0, 0);
            }
        __syncthreads();
    }

#pragma unroll
    for (int ni = 0; ni < NT; ++ni) {
        int col = n0 + wave_n + ni * 16 + lm;
        float bv = bias[col];
#pragma unroll
        for (int mi = 0; mi < MT; ++mi) {
            int rowbase = m0 + wave_m + mi * 16 + quad * 4;
#pragma unroll
            for (int r = 0; r < 4; ++r) {
                float g = gelu_f(acc[mi][ni][r] + bv);
                if (EMIT_F32) {
                    ((float*)Cptr)[(size_t)(rowbase + r) * N + col] = g;
                } else {
                    ((unsigned int*)Cptr)[(size_t)(rowbase + r) * N + col] = split_pack(g);
                }
            }
        }
    }
}

// ======================= VQ prep =======================
__global__ __launch_bounds__(256)
void prep_emb(const float* __restrict__ emb, _Float16* __restrict__ ebh,
              _Float16* __restrict__ ebl)
{
    int e = blockIdx.x * 256 + threadIdx.x;   // 65536
    int c = e >> 10, n = e & 1023;
    float v = emb[e];
    _Float16 h = (_Float16)v;
    _Float16 l = (_Float16)(v - (float)h);
    ebh[(size_t)n * DC + c] = h;
    ebl[(size_t)n * DC + c] = l;
}

__global__ __launch_bounds__(256)
void e2_kernel(const float* __restrict__ emb, float* __restrict__ e2)
{
    int n = blockIdx.x * 256 + threadIdx.x;   // 1024
    float s = 0.f;
#pragma unroll
    for (int c = 0; c < DC; ++c) { float e = emb[(size_t)c * NCODE + n]; s = fmaf(e, e, s); }
    e2[n] = s;
}

// ======================= VQ main (MFMA fp16x4 distances) =======================
__global__ __launch_bounds__(256, 2)
void vq_mfma_kernel(const float* __restrict__ lat, const float* __restrict__ emb,
                    const _Float16* __restrict__ ebh, const _Float16* __restrict__ ebl,
                    const float* __restrict__ e2,
                    float* __restrict__ quant_out, float* __restrict__ encidx_out,
                    int* __restrict__ codes_out, unsigned int* __restrict__ counts,
                    float* __restrict__ sum_sq)
{
    __shared__ _Float16 Ah[64][72], Al[64][72];
    __shared__ float e2s[NCODE];
    __shared__ float red_d[64][17];
    __shared__ int   red_i[64][17];
    __shared__ int   sidx[64];
    __shared__ float wred[4];

    const int tid = threadIdx.x, lane = tid & 63, wave = tid >> 6;
    const int lm = lane & 15, quad = lane >> 4;
    const int tok0 = blockIdx.x * 64;

#pragma unroll
    for (int i = 0; i < 4; ++i) { int k = tid + i * 256; e2s[k] = e2[k]; }
#pragma unroll
    for (int i = 0; i < 4; ++i) {
        int idx = tid + i * 256;
        int row = idx >> 4, c4 = (idx & 15) * 4;
        float4 v = *(const float4*)(lat + (size_t)(tok0 + row) * DC + c4);
        float vv[4] = {v.x, v.y, v.z, v.w};
        unsigned short h[4], l[4];
#pragma unroll
        for (int j = 0; j < 4; ++j) {
            _Float16 hh = (_Float16)vv[j];
            _Float16 ll = (_Float16)(vv[j] - (float)hh);
            h[j] = __builtin_bit_cast(unsigned short, hh);
            l[j] = __builtin_bit_cast(unsigned short, ll);
        }
        uint2 ph, pl;
        ph.x = (unsigned int)h[0] | ((unsigned int)h[1] << 16);
        ph.y = (unsigned int)h[2] | ((unsigned int)h[3] << 16);
        pl.x = (unsigned int)l[0] | ((unsigned int)l[1] << 16);
        pl.y = (unsigned int)l[2] | ((unsigned int)l[3] << 16);
        *(uint2*)&Ah[row][c4] = ph;
        *(uint2*)&Al[row][c4] = pl;
    }
    __syncthreads();

    float bd[4]; int bi[4];
#pragma unroll
    for (int r = 0; r < 4; ++r) { bd[r] = INFINITY; bi[r] = 0; }

    for (int k0 = 0; k0 < NCODE; k0 += 64) {
        f32x4 acc[4];
#pragma unroll
        for (int ni = 0; ni < 4; ++ni) acc[ni] = (f32x4)(0.f);
#pragma unroll
        for (int ks = 0; ks < 2; ++ks) {
            half8 ah = *(const half8*)&Ah[wave * 16 + lm][ks * 32 + quad * 8];
            half8 al = *(const half8*)&Al[wave * 16 + lm][ks * 32 + quad * 8];
#pragma unroll
            for (int ni = 0; ni < 4; ++ni) {
                int code = k0 + ni * 16 + lm;
                half8 bh = *(const half8*)(ebh + (size_t)code * DC + ks * 32 + quad * 8);
                half8 bl = *(const half8*)(ebl + (size_t)code * DC + ks * 32 + quad * 8);
                acc[ni] = __builtin_amdgcn_mfma_f32_16x16x32_f16(ah, bh, acc[ni], 0, 0, 0);
                acc[ni] = __builtin_amdgcn_mfma_f32_16x16x32_f16(ah, bl, acc[ni], 0, 0, 0);
                acc[ni] = __builtin_amdgcn_mfma_f32_16x16x32_f16(al, bh, acc[ni], 0, 0, 0);
                acc[ni] = __builtin_amdgcn_mfma_f32_16x16x32_f16(al, bl, acc[ni], 0, 0, 0);
            }
        }
#pragma unroll
        for (int ni = 0; ni < 4; ++ni) {
            int code = k0 + ni * 16 + lm;
            float ee = e2s[code];
#pragma unroll
            for (int r = 0; r < 4; ++r) {
                float d = ee - 2.f * acc[ni][r];
                if (d < bd[r]) { bd[r] = d; bi[r] = code; }
            }
        }
    }

#pragma unroll
    for (int r = 0; r < 4; ++r) {
        int t = wave * 16 + quad * 4 + r;
        red_d[t][lm] = bd[r];
        red_i[t][lm] = bi[r];
    }
    __syncthreads();
    if (tid < 64) {
        float d0 = red_d[tid][0]; int i0 = red_i[tid][0];
        for (int x = 1; x < 16; ++x) {
            float d = red_d[tid][x]; int i = red_i[tid][x];
            if (d < d0 || (d == d0 && i < i0)) { d0 = d; i0 = i; }
        }
        sidx[tid] = i0;
        encidx_out[tok0 + tid] = (float)i0;
        codes_out[tok0 + tid] = i0;
        atomicAdd(&counts[i0], 1u);
    }
    __syncthreads();

    const int t2 = tid >> 2;
    const int g  = tid & 3;
    const int code = sidx[t2];
    float lsum = 0.f;
#pragma unroll
    for (int q = 0; q < 4; ++q) {
        int c0 = g * 16 + q * 4;
        float4 xv = *(const float4*)(lat + (size_t)(tok0 + t2) * DC + c0);
        float xx[4] = {xv.x, xv.y, xv.z, xv.w};
        float qv[4];
#pragma unroll
        for (int j = 0; j < 4; ++j) {
            qv[j] = emb[(size_t)(c0 + j) * NCODE + code];
            float df = qv[j] - xx[j];
            lsum = fmaf(df, df, lsum);
        }
        float4 v; v.x = qv[0]; v.y = qv[1]; v.z = qv[2]; v.w = qv[3];
        *(float4*)(quant_out + (size_t)(tok0 + t2) * DC + c0) = v;
    }
#pragma unroll
    for (int o = 32; o > 0; o >>= 1) lsum += __shfl_down(lsum, o);
    if ((tid & 63) == 0) wred[tid >> 6] = lsum;
    __syncthreads();
    if (tid == 0) atomicAdd(sum_sq, wred[0] + wred[1] + wred[2] + wred[3]);
}

// ======================= dw via skew-proof bucketing =======================
__global__ __launch_bounds__(1024)
void scan_kernel(const unsigned int* __restrict__ counts, int* __restrict__ offs,
                 unsigned int* __restrict__ cursors)
{
    __shared__ int s[1024];
    int t = threadIdx.x;
    int v = (int)counts[t];
    s[t] = v; __syncthreads();
    for (int d = 1; d < 1024; d <<= 1) {
        int x = (t >= d) ? s[t - d] : 0;
        __syncthreads();
        s[t] += x;
        __syncthreads();
    }
    offs[t] = s[t] - v;          // exclusive prefix
    cursors[t] = (unsigned int)(s[t] - v);
}

// block-local histogram scatter: <= #distinct-codes global atomics per block
__global__ __launch_bounds__(256)
void scatter_kernel(const int* __restrict__ codes, unsigned int* __restrict__ cursors,
                    int* __restrict__ bucket)
{
    __shared__ unsigned int hist[NCODE];
    __shared__ unsigned int basea[NCODE];
    int tid = threadIdx.x;
    for (int i = tid; i < NCODE; i += 256) hist[i] = 0;
    __syncthreads();
    int t = blockIdx.x * 256 + tid;
    int c = codes[t];
    unsigned int rank = atomicAdd(&hist[c], 1u);   // LDS atomic -> local rank
    __syncthreads();
    for (int i = tid; i < NCODE; i += 256) {
        unsigned int h = hist[i];
        if (h > 0) basea[i] = atomicAdd(&cursors[i], h);
    }
    __syncthreads();
    bucket[basea[c] + rank] = t;
}

// grid (NCODE, NTOK/DWCHUNK); each block reduces <= DWCHUNK tokens of one code
__global__ __launch_bounds__(256)
void dw_kernel(const float* __restrict__ lat, const int* __restrict__ bucket,
               const int* __restrict__ offs, const unsigned int* __restrict__ counts,
               float* __restrict__ dw)
{
    __shared__ float sred[4][64];
    const int code = blockIdx.x;
    const int n = (int)counts[code];
    const int start = blockIdx.y * DWCHUNK;
    if (start >= n) return;
    const int cnt = min(n - start, DWCHUNK);
    const int base = offs[code] + start;
    const int lane = threadIdx.x & 63, wave = threadIdx.x >> 6;

    float s0 = 0.f, s1 = 0.f, s2 = 0.f, s3 = 0.f;
    int i = wave;
    for (; i + 12 < cnt; i += 16) {
        int t0 = bucket[base + i];
        int t1 = bucket[base + i + 4];
        int t2 = bucket[base + i + 8];
        int t3 = bucket[base + i + 12];
        s0 += lat[(size_t)t0 * DC + lane];
        s1 += lat[(size_t)t1 * DC + lane];
        s2 += lat[(size_t)t2 * DC + lane];
        s3 += lat[(size_t)t3 * DC + lane];
    }
    for (; i < cnt; i += 4)
        s0 += lat[(size_t)bucket[base + i] * DC + lane];

    sred[wave][lane] = (s0 + s1) + (s2 + s3);
    __syncthreads();
    if (threadIdx.x < 64) {
        float tot = sred[0][lane] + sred[1][lane] + sred[2][lane] + sred[3][lane];
        atomicAdd(&dw[(size_t)lane * NCODE + code], tot);
    }
}

// ======================= finalize =======================
__global__ __launch_bounds__(1024)
void finalize_kernel(const unsigned int* __restrict__ counts,
                     const float* __restrict__ dw,
                     const float* __restrict__ ema_ch,
                     const float* __restrict__ ema_dw,
                     const float* __restrict__ sum_sq,
                     float* __restrict__ out_loss, float* __restrict__ out_perp,
                     float* __restrict__ out_newemb)
{
    __shared__ float sred[1024];
    const int k = threadIdx.x;
    const float debias = (float)(1.0 - pow(0.99, 1001.0));
    float cnt = (float)counts[k];
    float cs  = (ema_ch[k] * 0.99f + cnt * 0.01f) / debias;

    sred[k] = cs; __syncthreads();
    for (int s = 512; s > 0; s >>= 1) { if (k < s) sred[k] += sred[k + s]; __syncthreads(); }
    float n = sred[0];
    __syncthreads();

    float p = cnt / 98304.0f;
    sred[k] = p * logf(p + 1e-10f);
    __syncthreads();
    for (int s = 512; s > 0; s >>= 1) { if (k < s) sred[k] += sred[k + s]; __syncthreads(); }
    if (k == 0) {
        out_perp[0] = expf(-sred[0]);
        out_loss[0] = 0.25f * sum_sq[0] / 6291456.0f;
    }

    float stable = (cs + 1e-5f) / (n + 1024.0f * 1e-5f) * n;
#pragma unroll
    for (int c = 0; c < 64; ++c) {
        size_t o = (size_t)c * 1024 + k;
        out_newemb[o] = ((ema_dw[o] * 0.99f + dw[o] * 0.01f) / debias) / stable;
    }
}

extern "C" void kernel_launch(void* const* d_in, const int* in_sizes, int n_in,
                              void* d_out, int out_size, void* d_ws, size_t ws_size,
                              hipStream_t stream)
{
    (void)in_sizes; (void)n_in; (void)out_size; (void)ws_size;
    const float* states = (const float*)d_in[0];
    const float* w_se   = (const float*)d_in[1];
    const float* b_se   = (const float*)d_in[2];
    const float* w0     = (const float*)d_in[3];
    const float* b0     = (const float*)d_in[4];
    const float* w1     = (const float*)d_in[5];
    const float* b1     = (const float*)d_in[6];
    const float* w2     = (const float*)d_in[7];
    const float* b2     = (const float*)d_in[8];
    const float* emb    = (const float*)d_in[9];
    const float* ema_ch = (const float*)d_in[10];
    const float* ema_dw = (const float*)d_in[11];

    float* out        = (float*)d_out;
    float* q_out      = out;                    // 6291456
    float* loss_out   = out + 6291456;          // 1
    float* perp_out   = out + 6291457;          // 1
    float* idx_out    = out + 6291458;          // 98304
    float* newemb_out = out + 6389762;          // 65536

    // ---- workspace layout (zeroed prefix first) ----
    char* ws = (char*)d_ws;
    size_t o = 0;
    unsigned int* counts  = (unsigned int*)(ws + o); o += 4096;
    unsigned int* cursors = (unsigned int*)(ws + o); o += 4096;
    float*        sumsq   = (float*)(ws + o);        o += 256;
    float*        dwb     = (float*)(ws + o);        o += (size_t)DC * NCODE * 4;  // zeroed
    const size_t ZERO_BYTES = o;                     // 270592
    int*          offs    = (int*)(ws + o);          o += 4096;
    int*          codes   = (int*)(ws + o);          o += (size_t)NTOK * 4;
    int*          bucket  = (int*)(ws + o);          o += (size_t)NTOK * 4;
    float*        e2b     = (float*)(ws + o);        o += 4096;
    _Float16*     ebh     = (_Float16*)(ws + o);     o += (size_t)NCODE * DC * 2;
    _Float16*     ebl     = (_Float16*)(ws + o);     o += (size_t)NCODE * DC * 2;
    unsigned int* wse_t   = (unsigned int*)(ws + o); o += (size_t)DIN * DE * 4;
    unsigned int* w0t     = (unsigned int*)(ws + o); o += (size_t)DE * DH * 4;
    unsigned int* w1t     = (unsigned int*)(ws + o); o += (size_t)DH * DH * 4;
    unsigned int* w2t     = (unsigned int*)(ws + o); o += (size_t)DH * DC * 4;
    unsigned int* bufA    = (unsigned int*)(ws + o); o += (size_t)CHUNK * DE * 4;
    unsigned int* bufB    = (unsigned int*)(ws + o); o += (size_t)CHUNK * DH * 4;
    float*        lat     = (float*)(ws + o);        o += (size_t)NTOK * DC * 4;

    hipMemsetAsync(d_ws, 0, ZERO_BYTES, stream);

    // weight/codebook prep (tiny)
    transpose_split<<<dim3((DIN * DE + 255) / 256), dim3(256), 0, stream>>>(w_se, wse_t, DIN, DE);
    transpose_split<<<dim3((DE * DH + 255) / 256), dim3(256), 0, stream>>>(w0, w0t, DE, DH);
    transpose_split<<<dim3((DH * DH + 255) / 256), dim3(256), 0, stream>>>(w1, w1t, DH, DH);
    transpose_split<<<dim3((DH * DC + 255) / 256), dim3(256), 0, stream>>>(w2, w2t, DH, DC);
    prep_emb<<<dim3(256), dim3(256), 0, stream>>>(emb, ebh, ebl);
    e2_kernel<<<dim3(4), dim3(256), 0, stream>>>(emb, e2b);

    dim3 blk(256);
    const int MBLK = CHUNK / 128;
    for (int c = 0; c < NTOK / CHUNK; ++c) {
        size_t off = (size_t)c * CHUNK;
        gemm_f16x3<128, true,  false><<<dim3(DE / 128, MBLK), blk, 0, stream>>>(
            states + off * DIN, wse_t, b_se, bufA, CHUNK, DE, DIN);
        gemm_f16x3<128, false, false><<<dim3(DH / 128, MBLK), blk, 0, stream>>>(
            bufA, w0t, b0, bufB, CHUNK, DH, DE);
        gemm_f16x3<128, false, false><<<dim3(DH / 128, MBLK), blk, 0, stream>>>(
            bufB, w1t, b1, bufA, CHUNK, DH, DH);
        gemm_f16x3<64,  false, true ><<<dim3(1, MBLK), blk, 0, stream>>>(
            bufA, w2t, b2, lat + off * DC, CHUNK, DC, DH);
    }

    vq_mfma_kernel<<<dim3(NTOK / 64), blk, 0, stream>>>(
        lat, emb, ebh, ebl, e2b, q_out, idx_out, codes, counts, sumsq);

    scan_kernel<<<dim3(1), dim3(1024), 0, stream>>>(counts, offs, cursors);
    scatter_kernel<<<dim3(NTOK / 256), blk, 0, stream>>>(codes, cursors, bucket);
    dw_kernel<<<dim3(NCODE, NTOK / DWCHUNK), blk, 0, stream>>>(lat, bucket, offs, counts, dwb);

    finalize_kernel<<<dim3(1), dim3(1024), 0, stream>>>(counts, dwb, ema_ch, ema_dw, sumsq,
                                                        loss_out, perp_out, newemb_out);
}